// Round 6
// baseline (408.738 us; speedup 1.0000x reference)
//
#include <hip/hip_runtime.h>
#include <math.h>

#define TOKENS 16384
#define HIDDEN 4096
#define NEXP   64
#define NCH    (HIDDEN / 32)     // 128 mfma k-chunks (full K per wave)
#define TPB    128               // 2 waves; grid = 512 -> 2 blocks/CU
#define TOKB   32                // 16 tokens per wave

typedef _Float16 half8 __attribute__((ext_vector_type(8)));
typedef float    f32x4 __attribute__((ext_vector_type(4)));

// Pre-pack W [64][4096] fp32 -> Wh/Wl fp16 in MFMA B-layout [kblock][expert][32k]
__global__ void w_prep(const float* __restrict__ W,
                       _Float16* __restrict__ Wh, _Float16* __restrict__ Wl) {
    int idx = blockIdx.x * blockDim.x + threadIdx.x;   // = e*4096 + k
    int e = idx >> 12;
    int k = idx & 4095;
    float v = W[idx];
    _Float16 h = (_Float16)v;                // RTN, 11-bit mantissa
    _Float16 l = (_Float16)(v - (float)h);   // residual
    size_t dst = (((size_t)(k >> 5) * NEXP) + e) * 32 + (k & 31);
    Wh[dst] = h;
    Wl[dst] = l;
}

__device__ __forceinline__ void split8(const float4& p0, const float4& p1,
                                       half8& h, half8& l) {
    const float v[8] = {p0.x, p0.y, p0.z, p0.w, p1.x, p1.y, p1.z, p1.w};
    #pragma unroll
    for (int j = 0; j < 8; ++j) {
        _Float16 hi = (_Float16)v[j];
        h[j] = hi;
        l[j] = (_Float16)(v[j] - (float)hi);
    }
}

// Fused: full-K logits (fp16 hi/lo split MFMA: Al*Bh + Ah*Bl + Ah*Bh) + top-2
// + softmax, no partials. A prefetched 2 chunks ahead (HBM), B 1 ahead (L2).
__global__ __launch_bounds__(TPB, 1) void router_fused(
    const float* __restrict__ x, const _Float16* __restrict__ Wh,
    const _Float16* __restrict__ Wl, float* __restrict__ out)
{
    __shared__ float lds[2][16][NEXP + 1];   // per-wave logit tile, padded

    const int tid  = threadIdx.x;
    const int lane = tid & 63;
    const int wv   = tid >> 6;       // 0..1
    const int e16  = lane & 15;
    const int quad = lane >> 4;

    const int tok0 = blockIdx.x * TOKB + wv * 16;

    f32x4 acc[4];
    #pragma unroll
    for (int n = 0; n < 4; ++n) acc[n] = (f32x4){0.f, 0.f, 0.f, 0.f};

    // A: lane holds x[tok0+e16][c*32 + quad*8 + j], j=0..7
    const float* xp = x + (size_t)(tok0 + e16) * HIDDEN + quad * 8;

    // A double-buffer, 2 chunks deep
    float4 a0[2], a1[2];
    a0[0] = *(const float4*)(xp);        a1[0] = *(const float4*)(xp + 4);
    a0[1] = *(const float4*)(xp + 32);   a1[1] = *(const float4*)(xp + 36);

    // B double-buffer, 1 chunk deep: [kblock][expert][32k], contiguous 1KB runs
    half8 bh[2][4], bl[2][4];
    {
        const size_t bo = (size_t)e16 * 32 + quad * 8;
        #pragma unroll
        for (int n = 0; n < 4; ++n) {
            bh[0][n] = *reinterpret_cast<const half8*>(Wh + bo + (size_t)n * 512);
            bl[0][n] = *reinterpret_cast<const half8*>(Wl + bo + (size_t)n * 512);
        }
    }

    #pragma unroll 2
    for (int c = 0; c < NCH; ++c) {
        const int cur = c & 1, nxt = cur ^ 1;

        half8 ah, al;
        split8(a0[cur], a1[cur], ah, al);

        if (c + 2 < NCH) {           // A prefetch, 2 ahead (covers HBM latency)
            a0[cur] = *(const float4*)(xp + (c + 2) * 32);
            a1[cur] = *(const float4*)(xp + (c + 2) * 32 + 4);
        }
        if (c + 1 < NCH) {           // B prefetch, 1 ahead (L2-resident)
            const size_t bo = ((size_t)(c + 1) * NEXP + e16) * 32 + quad * 8;
            #pragma unroll
            for (int n = 0; n < 4; ++n) {
                bh[nxt][n] = *reinterpret_cast<const half8*>(Wh + bo + (size_t)n * 512);
                bl[nxt][n] = *reinterpret_cast<const half8*>(Wl + bo + (size_t)n * 512);
            }
        }

        // 4 independent chains x 3 dependent MFMAs (small terms first)
        #pragma unroll
        for (int n = 0; n < 4; ++n)
            acc[n] = __builtin_amdgcn_mfma_f32_16x16x32_f16(al, bh[cur][n], acc[n], 0, 0, 0);
        #pragma unroll
        for (int n = 0; n < 4; ++n)
            acc[n] = __builtin_amdgcn_mfma_f32_16x16x32_f16(ah, bl[cur][n], acc[n], 0, 0, 0);
        #pragma unroll
        for (int n = 0; n < 4; ++n)
            acc[n] = __builtin_amdgcn_mfma_f32_16x16x32_f16(ah, bh[cur][n], acc[n], 0, 0, 0);
    }

    // D layout: token-in-16 = quad*4+r, expert = n*16+e16. Stage to LDS tile.
    #pragma unroll
    for (int n = 0; n < 4; ++n)
        #pragma unroll
        for (int r = 0; r < 4; ++r)
            lds[wv][quad * 4 + r][n * 16 + e16] = acc[n][r];
    __syncthreads();

    // lanes 0-15 of each wave: top-2 + softmax over this wave's 16 tokens
    if (lane < 16) {
        float v1 = -INFINITY, v2 = -INFINITY;
        int i1 = 0, i2 = 0;
        #pragma unroll 8
        for (int e = 0; e < NEXP; ++e) {
            float v = lds[wv][lane][e];   // stride 65: conflict-free
            if (v > v1)      { v2 = v1; i2 = i1; v1 = v; i1 = e; }
            else if (v > v2) { v2 = v;  i2 = e; }
        }
        float e2 = expf(v2 - v1);
        float d  = 1.f / (1.f + e2);
        int tok = tok0 + lane;
        out[tok * 2 + 0] = d;
        out[tok * 2 + 1] = e2 * d;
        out[2 * TOKENS + tok * 2 + 0] = (float)i1;
        out[2 * TOKENS + tok * 2 + 1] = (float)i2;
    }
}

extern "C" void kernel_launch(void* const* d_in, const int* in_sizes, int n_in,
                              void* d_out, int out_size, void* d_ws, size_t ws_size,
                              hipStream_t stream) {
    const float* x = (const float*)d_in[0];     // [16384, 4096]
    const float* W = (const float*)d_in[1];     // [64, 4096]
    float* out = (float*)d_out;

    _Float16* Wh = (_Float16*)d_ws;                       // 512 KB
    _Float16* Wl = Wh + (size_t)NEXP * HIDDEN;            // 512 KB

    w_prep<<<(NEXP * HIDDEN) / 256, 256, 0, stream>>>(W, Wh, Wl);
    router_fused<<<TOKENS / TOKB, TPB, 0, stream>>>(x, Wh, Wl, out);
}